// Round 4
// baseline (363.911 us; speedup 1.0000x reference)
//
#include <hip/hip_runtime.h>

typedef __attribute__((ext_vector_type(8))) short bf16x8;
typedef __attribute__((ext_vector_type(4))) float f32x4;

#define T_SEQ 2048
#define EXPM10 4.5399929762484854e-05f  // exp(-10)

__device__ __forceinline__ unsigned short f2bf(float f) {
    unsigned int u = __builtin_bit_cast(unsigned int, f);
    u += 0x7fffu + ((u >> 16) & 1u);
    return (unsigned short)(u >> 16);
}
__device__ __forceinline__ float bf2f(unsigned short u) {
    return __builtin_bit_cast(float, (unsigned int)u << 16);
}

__device__ __forceinline__ void async16(void* lds, const void* g) {
    __builtin_amdgcn_global_load_lds(
        (__attribute__((address_space(1))) void*)g,
        (__attribute__((address_space(3))) void*)lds, 16, 0, 0);
}

// fp32 -> bf16, 4 elems/thread (x activation)
__global__ __launch_bounds__(256) void cvt_bf16(const float* __restrict__ src,
                                                unsigned short* __restrict__ dst, int n4) {
    int i = blockIdx.x * 256 + threadIdx.x;
    if (i < n4) {
        float4 v = ((const float4*)src)[i];
        ushort4 r;
        r.x = f2bf(v.x); r.y = f2bf(v.y); r.z = f2bf(v.z); r.w = f2bf(v.w);
        ((ushort4*)dst)[i] = r;
    }
}

// all 4 weight matrices in one dispatch: wq/wk/wv -> contiguous wqkv, wo -> wob
__global__ __launch_bounds__(256) void cvt_w(const float* __restrict__ wq,
                                             const float* __restrict__ wk,
                                             const float* __restrict__ wv,
                                             const float* __restrict__ wo,
                                             unsigned short* __restrict__ wqkv,
                                             unsigned short* __restrict__ wob) {
    int which = blockIdx.x >> 10;
    int i = (blockIdx.x & 1023) * 256 + threadIdx.x;
    const float* src = which == 0 ? wq : which == 1 ? wk : which == 2 ? wv : wo;
    unsigned short* dst = which < 3 ? wqkv + (size_t)which * 1048576 : wob;
    float4 v = ((const float4*)src)[i];
    ushort4 r;
    r.x = f2bf(v.x); r.y = f2bf(v.y); r.z = f2bf(v.z); r.w = f2bf(v.w);
    ((ushort4*)dst)[i] = r;
}

// Fused QKV projection, BK=64 two-stage staging.
// out[m][n] = sum_k x[m][k]*wqkv[n][k], M=8192, N=3072, K=1024.
__global__ __launch_bounds__(256) void gemm_qkv(const unsigned short* __restrict__ A,
                                                const unsigned short* __restrict__ B,
                                                unsigned short* __restrict__ Qb,
                                                unsigned short* __restrict__ Kb,
                                                unsigned short* __restrict__ Vtb) {
    __shared__ unsigned short As[2][4096];  // [stage][128 rows x 32 k]
    __shared__ unsigned short Bs[2][4096];
    const int K = 1024;
    int m0 = blockIdx.y * 128, n0 = blockIdx.x * 128;
    int tid = threadIdx.x;
    int wave = tid >> 6, lane = tid & 63;
    int r = lane & 15, q = lane >> 4;
    int wr = wave >> 1, wc = wave & 1;

    f32x4 acc[4][4];
#pragma unroll
    for (int i = 0; i < 4; i++)
#pragma unroll
        for (int j = 0; j < 4; j++) acc[i][j] = (f32x4){0.f, 0.f, 0.f, 0.f};

    int row = tid >> 2, kk = (tid & 3) << 3;      // i=0 rows 0..63 handled by tid<256/4...
    for (int k0 = 0; k0 < K; k0 += 64) {
#pragma unroll
        for (int s = 0; s < 2; s++)
#pragma unroll
            for (int i = 0; i < 2; i++) {
                int li = i * 256 + tid;
                int rw = li >> 2, kc = (li & 3) << 3;
                async16(&As[s][i * 2048 + wave * 512], &A[(size_t)(m0 + rw) * K + k0 + s * 32 + kc]);
                async16(&Bs[s][i * 2048 + wave * 512], &B[(size_t)(n0 + rw) * K + k0 + s * 32 + kc]);
            }
        __syncthreads();
#pragma unroll
        for (int s = 0; s < 2; s++) {
            bf16x8 af[4], bfr[4];
#pragma unroll
            for (int mi = 0; mi < 4; mi++)
                af[mi] = *(const bf16x8*)&As[s][(wr * 64 + mi * 16 + r) * 32 + q * 8];
#pragma unroll
            for (int ni = 0; ni < 4; ni++)
                bfr[ni] = *(const bf16x8*)&Bs[s][(wc * 64 + ni * 16 + r) * 32 + q * 8];
#pragma unroll
            for (int mi = 0; mi < 4; mi++)
#pragma unroll
                for (int ni = 0; ni < 4; ni++)
                    acc[mi][ni] = __builtin_amdgcn_mfma_f32_16x16x32_bf16(
                        af[mi], bfr[ni], acc[mi][ni], 0, 0, 0);
        }
        __syncthreads();
    }

#pragma unroll
    for (int mi = 0; mi < 4; mi++) {
#pragma unroll
        for (int ni = 0; ni < 4; ni++) {
#pragma unroll
            for (int rr = 0; rr < 4; rr++) {
                int gm = m0 + wr * 64 + mi * 16 + q * 4 + rr;
                int gn = n0 + wc * 64 + ni * 16 + r;
                float v = acc[mi][ni][rr];
                int b = gm >> 11, t = gm & 2047;
                int sel = gn >> 10, nn = gn & 1023;
                int h = nn >> 6, d = nn & 63;
                if (sel == 0)
                    Qb[((size_t)(b * 16 + h) * 2048 + t) * 64 + d] = f2bf(v);
                else if (sel == 1)
                    Kb[((size_t)(b * 16 + h) * 2048 + t) * 64 + d] = f2bf(v);
                else
                    Vtb[((size_t)(b * 16 + h) * 64 + d) * 2048 + t] = f2bf(v);
            }
        }
    }
}

// Final projection, BK=64: out[m][n] = sum_k Y[m][k]*wo[n][k], fp32 out.
__global__ __launch_bounds__(256) void gemm_out(const unsigned short* __restrict__ A,
                                                const unsigned short* __restrict__ B,
                                                float* __restrict__ out) {
    __shared__ unsigned short As[2][4096];
    __shared__ unsigned short Bs[2][4096];
    const int K = 1024;
    int m0 = blockIdx.y * 128, n0 = blockIdx.x * 128;
    int tid = threadIdx.x;
    int wave = tid >> 6, lane = tid & 63;
    int r = lane & 15, q = lane >> 4;
    int wr = wave >> 1, wc = wave & 1;

    f32x4 acc[4][4];
#pragma unroll
    for (int i = 0; i < 4; i++)
#pragma unroll
        for (int j = 0; j < 4; j++) acc[i][j] = (f32x4){0.f, 0.f, 0.f, 0.f};

    for (int k0 = 0; k0 < K; k0 += 64) {
#pragma unroll
        for (int s = 0; s < 2; s++)
#pragma unroll
            for (int i = 0; i < 2; i++) {
                int li = i * 256 + tid;
                int rw = li >> 2, kc = (li & 3) << 3;
                async16(&As[s][i * 2048 + wave * 512], &A[(size_t)(m0 + rw) * K + k0 + s * 32 + kc]);
                async16(&Bs[s][i * 2048 + wave * 512], &B[(size_t)(n0 + rw) * K + k0 + s * 32 + kc]);
            }
        __syncthreads();
#pragma unroll
        for (int s = 0; s < 2; s++) {
            bf16x8 af[4], bfr[4];
#pragma unroll
            for (int mi = 0; mi < 4; mi++)
                af[mi] = *(const bf16x8*)&As[s][(wr * 64 + mi * 16 + r) * 32 + q * 8];
#pragma unroll
            for (int ni = 0; ni < 4; ni++)
                bfr[ni] = *(const bf16x8*)&Bs[s][(wc * 64 + ni * 16 + r) * 32 + q * 8];
#pragma unroll
            for (int mi = 0; mi < 4; mi++)
#pragma unroll
                for (int ni = 0; ni < 4; ni++)
                    acc[mi][ni] = __builtin_amdgcn_mfma_f32_16x16x32_bf16(
                        af[mi], bfr[ni], acc[mi][ni], 0, 0, 0);
        }
        __syncthreads();
    }

#pragma unroll
    for (int mi = 0; mi < 4; mi++)
#pragma unroll
        for (int ni = 0; ni < 4; ni++)
#pragma unroll
            for (int rr = 0; rr < 4; rr++) {
                int gm = m0 + wr * 64 + mi * 16 + q * 4 + rr;
                int gn = n0 + wc * 64 + ni * 16 + r;
                out[(size_t)gm * 1024 + gn] = acc[mi][ni][rr];
            }
}

// Suffix sums of V at 64-key granularity: SV[bh][j][d] = sum_{k >= 64j} V[bh][k][d]
__global__ __launch_bounds__(256) void suffix_sv(const unsigned short* __restrict__ Vt,
                                                 float* __restrict__ SV) {
    __shared__ float bsum[32][64];
    int bh = blockIdx.x;
    int d = threadIdx.x & 63, c = threadIdx.x >> 6;
    const unsigned short* base = Vt + ((size_t)bh * 64 + d) * T_SEQ;
#pragma unroll
    for (int jj = 0; jj < 8; jj++) {
        int j = c * 8 + jj;
        float s = 0.f;
#pragma unroll
        for (int t8 = 0; t8 < 8; t8++) {
            bf16x8 v = *(const bf16x8*)(base + j * 64 + t8 * 8);
#pragma unroll
            for (int e = 0; e < 8; e++) s += bf2f((unsigned short)v[e]);
        }
        bsum[j][d] = s;
    }
    __syncthreads();
    if (threadIdx.x < 64) {
        float run = 0.f;
        for (int j = 31; j >= 0; j--) {
            run += bsum[j][d];
            SV[((size_t)bh * 32 + j) * 64 + d] = run;
        }
    }
}

// Flash attention, transposed-S, no-max softmax, 128-query Q-tile:
// each of 4 waves owns 2 query groups of 16 (g=0: q0+w*16+r, g=1: q0+64+w*16+r).
// K/V staged once per 64-key tile feeds both groups (2x MFMA per barrier pair).
// Group g streams keys < 64*(2qi+g+1); the rest is the exact analytic -10 tail.
#define KST 72
#define VST 72
#define PST 72
__global__ __launch_bounds__(256) void attn(const unsigned short* __restrict__ Q,
                                            const unsigned short* __restrict__ Kg,
                                            const unsigned short* __restrict__ Vt,
                                            const float* __restrict__ SV,
                                            unsigned short* __restrict__ Y) {
    __shared__ unsigned short Ks[64 * KST];       // [key][d]
    __shared__ unsigned short Vs[64 * VST];       // [d][key]
    __shared__ unsigned short Ps[8 * 16 * PST];   // per (wave,g): [query][key]
    int bh = blockIdx.y;
    int qi = 15 - blockIdx.x;  // heavy tiles first
    int q0 = qi * 128;
    int tid = threadIdx.x, wave = tid >> 6, lane = tid & 63;
    int r = lane & 15, qd = lane >> 4;
    int query0 = q0 + wave * 16 + r;
    int query1 = query0 + 64;

    const unsigned short* qptr = Q + ((size_t)bh * T_SEQ + query0) * 64 + qd * 8;
    bf16x8 qf00 = *(const bf16x8*)qptr;
    bf16x8 qf01 = *(const bf16x8*)(qptr + 32);
    bf16x8 qf10 = *(const bf16x8*)(qptr + 64 * 64);
    bf16x8 qf11 = *(const bf16x8*)(qptr + 64 * 64 + 32);

    float l0 = 0.f, l1 = 0.f;
    f32x4 o0[4], o1[4];
#pragma unroll
    for (int n = 0; n < 4; n++) { o0[n] = (f32x4){0.f,0.f,0.f,0.f}; o1[n] = o0[n]; }

    int srow = tid >> 2, scol = (tid & 3) * 16;
    const unsigned short* kg = Kg + ((size_t)bh * T_SEQ + srow) * 64 + scol;
    const unsigned short* vg = Vt + ((size_t)bh * 64 + srow) * T_SEQ + scol;
    const float scale = 0.125f;

    unsigned short* ps0 = &Ps[(wave * 2 + 0) * 16 * PST];
    unsigned short* ps1 = &Ps[(wave * 2 + 1) * 16 * PST];

    // prefetch tile 0
    bf16x8 pk0 = *(const bf16x8*)(kg);
    bf16x8 pk1 = *(const bf16x8*)(kg + 8);
    bf16x8 pv0 = *(const bf16x8*)(vg);
    bf16x8 pv1 = *(const bf16x8*)(vg + 8);

    int iters = 2 * qi + 2;
    for (int it = 0; it < iters; ++it) {
        bool g0run = (it < iters - 1);  // last tile is fully masked for group 0
        __syncthreads();
        *(bf16x8*)&Ks[srow * KST + scol]     = pk0;
        *(bf16x8*)&Ks[srow * KST + scol + 8] = pk1;
        *(bf16x8*)&Vs[srow * VST + scol]     = pv0;
        *(bf16x8*)&Vs[srow * VST + scol + 8] = pv1;
        __syncthreads();
        if (it + 1 < iters) {
            size_t kn = (size_t)(it + 1) * 64;
            pk0 = *(const bf16x8*)(kg + kn * 64);
            pk1 = *(const bf16x8*)(kg + kn * 64 + 8);
            pv0 = *(const bf16x8*)(vg + kn);
            pv1 = *(const bf16x8*)(vg + kn + 8);
        }

        int k0 = it * 64;
        // S^T: K-frags read once, used by both query groups
        f32x4 st0[4], st1[4];
#pragma unroll
        for (int t = 0; t < 4; t++) {
            bf16x8 kf0 = *(const bf16x8*)&Ks[(t * 16 + r) * KST + qd * 8];
            bf16x8 kf1 = *(const bf16x8*)&Ks[(t * 16 + r) * KST + 32 + qd * 8];
            if (g0run) {
                st0[t] = (f32x4){0.f,0.f,0.f,0.f};
                st0[t] = __builtin_amdgcn_mfma_f32_16x16x32_bf16(kf0, qf00, st0[t], 0, 0, 0);
                st0[t] = __builtin_amdgcn_mfma_f32_16x16x32_bf16(kf1, qf01, st0[t], 0, 0, 0);
            }
            st1[t] = (f32x4){0.f,0.f,0.f,0.f};
            st1[t] = __builtin_amdgcn_mfma_f32_16x16x32_bf16(kf0, qf10, st1[t], 0, 0, 0);
            st1[t] = __builtin_amdgcn_mfma_f32_16x16x32_bf16(kf1, qf11, st1[t], 0, 0, 0);
        }

        // group 0: exp + mask + pack
        if (g0run) {
            float sum = 0.f;
            bool anymask = (k0 + 63 > q0 + wave * 16);
#pragma unroll
            for (int t = 0; t < 4; t++) {
                float p[4];
                if (anymask) {
#pragma unroll
                    for (int e = 0; e < 4; e++) {
                        int kgidx = k0 + t * 16 + qd * 4 + e;
                        float pe = __expf(st0[t][e] * scale);
                        p[e] = (kgidx <= query0) ? pe : EXPM10;
                        sum += p[e];
                    }
                } else {
#pragma unroll
                    for (int e = 0; e < 4; e++) { p[e] = __expf(st0[t][e] * scale); sum += p[e]; }
                }
                ushort4 pk;
                pk.x = f2bf(p[0]); pk.y = f2bf(p[1]); pk.z = f2bf(p[2]); pk.w = f2bf(p[3]);
                *(ushort4*)&ps0[r * PST + t * 16 + qd * 4] = pk;
            }
            l0 += sum;
        }
        // group 1
        {
            float sum = 0.f;
            bool anymask = (k0 + 63 > q0 + 64 + wave * 16);
#pragma unroll
            for (int t = 0; t < 4; t++) {
                float p[4];
                if (anymask) {
#pragma unroll
                    for (int e = 0; e < 4; e++) {
                        int kgidx = k0 + t * 16 + qd * 4 + e;
                        float pe = __expf(st1[t][e] * scale);
                        p[e] = (kgidx <= query1) ? pe : EXPM10;
                        sum += p[e];
                    }
                } else {
#pragma unroll
                    for (int e = 0; e < 4; e++) { p[e] = __expf(st1[t][e] * scale); sum += p[e]; }
                }
                ushort4 pk;
                pk.x = f2bf(p[0]); pk.y = f2bf(p[1]); pk.z = f2bf(p[2]); pk.w = f2bf(p[3]);
                *(ushort4*)&ps1[r * PST + t * 16 + qd * 4] = pk;
            }
            l1 += sum;
        }
        __builtin_amdgcn_sched_barrier(0);  // wave-private Ps: same-wave DS order

        // O^T += V * P^T : V-frags read once, used by both groups
        bf16x8 pf00, pf01, pf10, pf11;
        if (g0run) {
            pf00 = *(const bf16x8*)&ps0[r * PST + qd * 8];
            pf01 = *(const bf16x8*)&ps0[r * PST + 32 + qd * 8];
        }
        pf10 = *(const bf16x8*)&ps1[r * PST + qd * 8];
        pf11 = *(const bf16x8*)&ps1[r * PST + 32 + qd * 8];
#pragma unroll
        for (int n = 0; n < 4; n++) {
            bf16x8 vf0 = *(const bf16x8*)&Vs[(n * 16 + r) * VST + qd * 8];
            bf16x8 vf1 = *(const bf16x8*)&Vs[(n * 16 + r) * VST + 32 + qd * 8];
            if (g0run) {
                o0[n] = __builtin_amdgcn_mfma_f32_16x16x32_bf16(vf0, pf00, o0[n], 0, 0, 0);
                o0[n] = __builtin_amdgcn_mfma_f32_16x16x32_bf16(vf1, pf01, o0[n], 0, 0, 0);
            }
            o1[n] = __builtin_amdgcn_mfma_f32_16x16x32_bf16(vf0, pf10, o1[n], 0, 0, 0);
            o1[n] = __builtin_amdgcn_mfma_f32_16x16x32_bf16(vf1, pf11, o1[n], 0, 0, 0);
        }
    }

    int b = bh >> 4, h = bh & 15;
#pragma unroll
    for (int g = 0; g < 2; g++) {
        float l_i = g == 0 ? l0 : l1;
        l_i += __shfl_xor(l_i, 16);
        l_i += __shfl_xor(l_i, 32);
        int j = 2 * qi + g + 1;      // tail starts at key 64*j
        int query = g == 0 ? query0 : query1;
        f32x4* o = g == 0 ? o0 : o1;
        float pm = 0.f, tail_l = 0.f;
        float sv[4][4];
#pragma unroll
        for (int n = 0; n < 4; n++)
#pragma unroll
            for (int e = 0; e < 4; e++) sv[n][e] = 0.f;
        if (j < 32) {
            pm = EXPM10;
            tail_l = (float)(T_SEQ - 64 * j) * pm;
            const float* svp = SV + ((size_t)bh * 32 + j) * 64;
#pragma unroll
            for (int n = 0; n < 4; n++) {
                float4 f = *(const float4*)(svp + n * 16 + qd * 4);
                sv[n][0] = f.x; sv[n][1] = f.y; sv[n][2] = f.z; sv[n][3] = f.w;
            }
        }
        float inv = 1.0f / (l_i + tail_l);
#pragma unroll
        for (int n = 0; n < 4; n++) {
            ushort4 yk;
            yk.x = f2bf((o[n][0] + pm * sv[n][0]) * inv);
            yk.y = f2bf((o[n][1] + pm * sv[n][1]) * inv);
            yk.z = f2bf((o[n][2] + pm * sv[n][2]) * inv);
            yk.w = f2bf((o[n][3] + pm * sv[n][3]) * inv);
            *(ushort4*)&Y[(((size_t)b * T_SEQ + query) * 16 + h) * 64 + n * 16 + qd * 4] = yk;
        }
    }
}

extern "C" void kernel_launch(void* const* d_in, const int* in_sizes, int n_in,
                              void* d_out, int out_size, void* d_ws, size_t ws_size,
                              hipStream_t stream) {
    const float* x  = (const float*)d_in[0];
    const float* wq = (const float*)d_in[1];
    const float* wk = (const float*)d_in[2];
    const float* wv = (const float*)d_in[3];
    const float* wo = (const float*)d_in[4];

    char* ws = (char*)d_ws;
    const size_t MB = 1u << 20;
    unsigned short* xb   = (unsigned short*)(ws);            // 16 MB (reused as Yb)
    unsigned short* Qb   = (unsigned short*)(ws + 16 * MB);  // 16 MB
    unsigned short* Kb   = (unsigned short*)(ws + 32 * MB);  // 16 MB
    unsigned short* Vtb  = (unsigned short*)(ws + 48 * MB);  // 16 MB
    unsigned short* wqkv = (unsigned short*)(ws + 64 * MB);  // 6 MB
    unsigned short* wob  = (unsigned short*)(ws + 70 * MB);  // 2 MB -> 72 MB total
    unsigned short* Yb   = xb;
    float* SVf = (float*)d_out;  // scratch until final gemm overwrites d_out

    cvt_bf16<<<8192, 256, 0, stream>>>(x, xb, 2097152);
    cvt_w<<<4096, 256, 0, stream>>>(wq, wk, wv, wo, wqkv, wob);

    gemm_qkv<<<dim3(24, 64), 256, 0, stream>>>(xb, wqkv, Qb, Kb, Vtb);

    suffix_sv<<<64, 256, 0, stream>>>(Vtb, SVf);

    attn<<<dim3(16, 64), 256, 0, stream>>>(Qb, Kb, Vtb, SVf, Yb);

    gemm_out<<<dim3(8, 64), 256, 0, stream>>>(Yb, wob, (float*)d_out);
}